// Round 3
// baseline (317.471 us; speedup 1.0000x reference)
//
#include <hip/hip_runtime.h>

// out[b,c,h,w] = block_switch[h/8, w/8] ? -1.0f : image[b,c,h,w]
// image: [64, 3, 512, 512] fp32 ; block_switch: [64, 64] (bool -> int32 per harness)
//
// One float4 per lane per unroll step. A float4 starts at w = 4*k; 4k..4k+3
// share the same w/8 block (4k % 8 is 0 or 4) -> one mask lookup per float4.
//
// v4 changes vs v3 (total 316.5 us, kernel ~72 us of it):
//  - persistent grid: 2048 blocks (8/CU, one co-resident round) x 3
//    grid-stride iterations instead of 6144 one-shot blocks. Same memory
//    footprint per chunk (contiguous 32 KiB per block per iteration), but
//    block ramp/drain amortized 3x and the 16 KB mask stays L1-hot.
//  - UNROLL=8 kept (proven harmless; VGPR budget fine at 8 waves/SIMD).
//  - conditional image load kept (any realizable 64B-sector skip is free
//    read-traffic savings); nontemporal hints kept on streaming img/out.
// v3 post-mortem: UNROLL 4->8 was null -> kernel is NOT latency-limited;
// it sits near the mixed read+write BW ceiling (~403 MB dense-equivalent
// at ~5.9 TB/s + ~4 us ramp). This is the last structural overhead lever.

typedef float f32x4 __attribute__((ext_vector_type(4)));

#define W 512
#define H 512
#define MASK_W 64      // W / 8
#define TPB 256
#define UNROLL 8
#define NBLOCKS 2048   // 8 blocks/CU x 256 CUs

__global__ __launch_bounds__(TPB) void grid_crop_kernel(
    const f32x4* __restrict__ img,
    const int* __restrict__ mask,
    f32x4* __restrict__ out,
    int iters)
{
    for (int it = 0; it < iters; ++it) {
        // Each (it, block) pair owns a contiguous 2048-float4 (32 KiB) chunk.
        int base = (it * NBLOCKS + blockIdx.x) * (TPB * UNROLL) + threadIdx.x;

        // Phase 1: 8 independent mask loads (L1-resident after first iter).
        int m[UNROLL];
#pragma unroll
        for (int u = 0; u < UNROLL; ++u) {
            int idx  = base + u * TPB;
            int elem = idx << 2;                 // flat float index
            int w    = elem & (W - 1);           // 0..511
            int h    = (elem >> 9) & (H - 1);    // 0..511  (W == 512 == 2^9)
            m[u] = mask[(h >> 3) * MASK_W + (w >> 3)];
        }

        // Phase 2: 8 independent exec-masked image loads, all in flight.
        f32x4 v[UNROLL];
#pragma unroll
        for (int u = 0; u < UNROLL; ++u) {
            int idx = base + u * TPB;
            if (m[u] == 0) {
                v[u] = __builtin_nontemporal_load(&img[idx]);
            } else {
                v[u] = (f32x4){-1.0f, -1.0f, -1.0f, -1.0f};
            }
        }

        // Phase 3: dense streaming stores.
#pragma unroll
        for (int u = 0; u < UNROLL; ++u) {
            int idx = base + u * TPB;
            __builtin_nontemporal_store(v[u], &out[idx]);
        }
    }
}

// Tail kernel for any remainder elements (none for this problem's exact
// shape, but keeps kernel_launch correct for any out_size).
__global__ __launch_bounds__(TPB) void grid_crop_tail(
    const f32x4* __restrict__ img,
    const int* __restrict__ mask,
    f32x4* __restrict__ out,
    int start, int n4)
{
    int idx = start + blockIdx.x * blockDim.x + threadIdx.x;
    if (idx >= n4) return;
    int elem = idx << 2;
    int w = elem & (W - 1);
    int h = (elem >> 9) & (H - 1);
    int m = mask[(h >> 3) * MASK_W + (w >> 3)];
    f32x4 v;
    if (m == 0) {
        v = __builtin_nontemporal_load(&img[idx]);
    } else {
        v = (f32x4){-1.0f, -1.0f, -1.0f, -1.0f};
    }
    __builtin_nontemporal_store(v, &out[idx]);
}

extern "C" void kernel_launch(void* const* d_in, const int* in_sizes, int n_in,
                              void* d_out, int out_size, void* d_ws, size_t ws_size,
                              hipStream_t stream) {
    const f32x4* img  = (const f32x4*)d_in[0];
    const int*   mask = (const int*)d_in[1];
    f32x4*       out  = (f32x4*)d_out;

    int n4 = out_size >> 2;                      // 12,582,912 float4
    const int per_iter = NBLOCKS * TPB * UNROLL; // 4,194,304 float4
    int iters = n4 / per_iter;                   // 3 exact for this shape

    if (iters > 0) {
        grid_crop_kernel<<<NBLOCKS, TPB, 0, stream>>>(img, mask, out, iters);
    }

    int done = iters * per_iter;
    int rem  = n4 - done;
    if (rem > 0) {
        int tgrid = (rem + TPB - 1) / TPB;
        grid_crop_tail<<<tgrid, TPB, 0, stream>>>(img, mask, out, done, n4);
    }
}